// Round 1
// baseline (673.931 us; speedup 1.0000x reference)
//
#include <hip/hip_runtime.h>
#include <hip/hip_bf16.h>

constexpr int TT = 512, BB = 2048, NOUT = 8;
constexpr size_t DSTRIDE = (size_t)BB * TT * 24;   // bf16 elems per dir region

typedef __attribute__((ext_vector_type(8))) short bf16x8;
typedef __attribute__((ext_vector_type(4))) float f32x4;
typedef __attribute__((ext_vector_type(2))) _Float16 f16x2;

// fast device math: v_exp_f32 / v_rcp_f32 (1-ulp approx, no div sequence)
__device__ __forceinline__ float sigm(float x) {
    float e = __builtin_amdgcn_exp2f(x * -1.4426950408889634f);
    return __builtin_amdgcn_rcpf(1.f + e);
}
__device__ __forceinline__ float tanh_(float x) {
    float e = __builtin_amdgcn_exp2f(x * 2.8853900817779268f);
    return __builtin_fmaf(-2.f, __builtin_amdgcn_rcpf(e + 1.f), 1.f);
}
__device__ __forceinline__ unsigned short f2bf(float x) {
    __hip_bfloat16 h = __float2bfloat16(x);
    unsigned short s;
    __builtin_memcpy(&s, &h, 2);
    return s;
}
__device__ __forceinline__ f16x2 asf16x2(unsigned v) {
    f16x2 r; __builtin_memcpy(&r, &v, 4); return r;
}
__device__ __forceinline__ void wbar() { __builtin_amdgcn_wave_barrier(); }

// R11: the h-vector broadcast no longer round-trips through LDS banks.
// Per step: pack pair (h[2k],h[2k+1]) via 2 quad_perm DPP + v_cvt_pkrtz,
// then 12 ds_swizzle_b32 broadcasts (BitMode and=0, or=2j: per-32-lane-group,
// identity pair order -> wrp layout unchanged). The LDS write survives only
// as store staging (1x ds_write_b32 pair word, off the critical path).
// Removes cvt->ds_write->ds_read->waitcnt turnaround (~150-250 cyc) from the
// 512x-serial recurrence. h history LDS shrinks to u32[8*2*16] per wave.
// Everything else (MFMA D-tile dbuf pipeline, staging, stores) unchanged.
template <bool L0, bool LAST>
__global__ __launch_bounds__(256) void gru_mfma(
    const void* __restrict__ in_,        // L0: x [B][T][32] f32; else region0 (region1 at +DSTRIDE)
    const float* __restrict__ fmean, const float* __restrict__ fstd,
    const float* __restrict__ wih_g, const float* __restrict__ whh_g,
    const float* __restrict__ bih_g, const float* __restrict__ bhh_g,
    __hip_bfloat16* __restrict__ outbuf, float* __restrict__ lastbuf)
{
    constexpr int KIN = L0 ? 32 : 46;
    constexpr int KF  = L0 ? 1 : 2;

    // [tile t<5][kslot<8][lane m<16][8 shorts] staging for B-frags
    __shared__ __align__(16) short     wih_lds[5 * 8 * 16 * 8];
    __shared__ __align__(16) _Float16  whh_h[80 * 24];       // W_hh f16
    __shared__ __align__(16) float     xg_s[4][2][16 * 84];  // per-wave D dbuf
    __shared__ __align__(16) unsigned  hist32[4 * 8 * 2 * 16];  // store staging (pair words)
    __shared__ float bih_s[80], bhh_s[80];
    __shared__ __align__(16) float an_s[32], cn_s[32];

    const int tid = threadIdx.x, wv = tid >> 6, lane = tid & 63;
    const int bl = lane >> 5, u = lane & 31;
    const int m  = lane & 15, kg = lane >> 4;             // MFMA lane coords
    const int dir = blockIdx.y;
    const int bg  = blockIdx.x * 8 + wv * 2 + bl;

    const float* wih_d = wih_g + dir * 69 * KIN;
    const float* whh_d = whh_g + dir * 69 * 23;

    // ---- stage W_ih frags [t][kslot][m][8], col-remapped, zero-padded ----
    for (int idx = tid; idx < 5120; idx += 256) {
        int t = idx >> 10, r = idx & 1023;
        int kslot = r >> 7, mm = (r >> 3) & 15, j = r & 7;
        int row = t * 16 + mm, k = kslot * 8 + j;
        float v = 0.f;
        if (row < 69) {
            if constexpr (L0) {
                if (k < 32) v = wih_d[row * 32 + k];
            } else {
                if (k < 23) v = wih_d[row * 46 + k];                      // fwd
                else if (k >= 24 && k < 47) v = wih_d[row * 46 + k - 1];  // bwd
            }
        }
        wih_lds[idx] = (short)f2bf(v);
    }
    for (int idx = tid; idx < 80 * 24; idx += 256) {
        int j = idx / 24, k = idx - j * 24;
        whh_h[idx] = (j < 69 && k < 23) ? (_Float16)whh_d[j * 23 + k]
                                        : (_Float16)0.f;
    }
    for (int idx = tid; idx < 80; idx += 256) {
        bih_s[idx] = (idx < 69) ? bih_g[dir * 69 + idx] : 0.f;
        bhh_s[idx] = (idx < 69) ? bhh_g[dir * 69 + idx] : 0.f;
    }
    if (L0 && tid < 32) {
        float sd = fstd[tid];
        float sa = (sd == 0.f) ? 1.f : sd;        // std==0 -> 1
        float a  = (sa == 1.f) ? 0.f : 1.f / sa;  // adjusted std==1 -> zero
        an_s[tid] = a;
        cn_s[tid] = -fmean[tid] * a;
    }
    __syncthreads();   // only block-wide barrier

    // ---- per-lane W_hh rows (u, 23+u, 46+u) as f16 pairs -> 36 VGPRs ----
    unsigned wrp[3][12];
    float bh2;
    #pragma unroll
    for (int r = 0; r < 3; ++r) {
        int row = r * 23 + u;   // <= 77 < 80
        #pragma unroll
        for (int k = 0; k < 12; ++k)
            wrp[r][k] = *(const unsigned*)&whh_h[row * 24 + 2 * k];
    }
    bh2 = bhh_s[46 + u];   // n-row b_hh stays inside r*(...)
    // D-tile bias: b_ih (+ b_hh for r/z rows, which add outside the r gate)
    float bi5[5];
    #pragma unroll
    for (int t = 0; t < 5; ++t) {
        int n = t * 16 + m;
        bi5[t] = bih_s[n] + (n < 46 ? bhh_s[n] : 0.f);
    }

    // ---- B-fragments register-resident ----
    const bf16x8* bfrag = (const bf16x8*)wih_lds;   // [t*8+kslot][m]
    bf16x8 bfr[5][KF];
    #pragma unroll
    for (int t = 0; t < 5; ++t)
        #pragma unroll
        for (int kf = 0; kf < KF; ++kf)
            bfr[t][kf] = bfrag[(t * 8 + kf * 4 + kg) * 16 + m];

    float an8[L0 ? 8 : 1], cn8[L0 ? 8 : 1];
    if constexpr (L0) {
        #pragma unroll
        for (int j = 0; j < 8; ++j) {
            an8[j] = an_s[kg * 8 + j];
            cn8[j] = cn_s[kg * 8 + j];
        }
    }

    float* db0 = &xg_s[wv][0][0];
    float* db1 = &xg_s[wv][1][0];
    unsigned* histw = &hist32[wv * 8 * 2 * 16];
    const int ngroups = (LAST && dir == 1) ? 1 : 64;
    float hold = 0.f;

    // ---- store-phase lane constants (hoisted) ----
    int sarr[3], cparr[3], ldsoff[3];
    {
        int idx = lane & 31;
        #pragma unroll
        for (int c = 0; c < 3; ++c) {
            int p = idx + 32 * c;             // 0..95
            sarr[c]  = p / 12;
            cparr[c] = p - 12 * sarr[c];
            ldsoff[c] = (sarr[c] * 2 + bl) * 16 + cparr[c];
        }
    }
    unsigned short* dstbase = nullptr;
    if constexpr (!LAST)
        dstbase = (unsigned short*)outbuf + dir * DSTRIDE + (size_t)bg * TT * 24;

    // A-row coords: m = bl_a*8 + tl
    const int bl_a = m >> 3, tl = m & 7;
    const int b_a  = blockIdx.x * 8 + wv * 2 + bl_a;

    const unsigned short* r0 = (const unsigned short*)in_;
    const unsigned short* r1 = r0 + DSTRIDE;

    float4 xraw0, xraw1;                 // L0 raw x
    bf16x8 a0r, a1r;                     // !L0 bf16 frags

    // ---- load raw A data for group 0 ----
    {
        const int tg_a = dir ? (511 - tl) : tl;
        if constexpr (L0) {
            const float* xr = (const float*)in_ +
                              ((size_t)b_a * TT + tg_a) * 32 + kg * 8;
            xraw0 = *(const float4*)xr;
            xraw1 = *(const float4*)(xr + 4);
        } else {
            size_t rowoff = ((size_t)b_a * TT + tg_a) * 24;
            const unsigned short* p0 =
                (kg < 3) ? (r0 + rowoff + 8 * kg) : (r1 + rowoff);
            const unsigned short* p1 =
                (kg == 0) ? (r1 + rowoff + 8) : (r1 + rowoff + 16);
            a0r = *(const bf16x8*)p0;
            a1r = *(const bf16x8*)p1;
        }
    }

    // ---- prologue: MFMA for group 0 -> db0 ----
    {
        f32x4 acc[5];
        #pragma unroll
        for (int t = 0; t < 5; ++t)
            acc[t] = (f32x4){bi5[t], bi5[t], bi5[t], bi5[t]};
        if constexpr (L0) {
            float xv[8] = {xraw0.x, xraw0.y, xraw0.z, xraw0.w,
                           xraw1.x, xraw1.y, xraw1.z, xraw1.w};
            bf16x8 afr;
            #pragma unroll
            for (int j = 0; j < 8; ++j)
                afr[j] = (short)f2bf(xv[j] * an8[j] + cn8[j]);
            #pragma unroll
            for (int t = 0; t < 5; ++t)
                acc[t] = __builtin_amdgcn_mfma_f32_16x16x32_bf16(afr, bfr[t][0],
                                                                 acc[t], 0, 0, 0);
        } else {
            bf16x8 a0u = a0r;
            bf16x8 a1u = (kg >= 2) ? (bf16x8){0,0,0,0,0,0,0,0} : a1r;
            #pragma unroll
            for (int t = 0; t < 5; ++t) {
                acc[t] = __builtin_amdgcn_mfma_f32_16x16x32_bf16(a0u, bfr[t][0],
                                                                 acc[t], 0, 0, 0);
                acc[t] = __builtin_amdgcn_mfma_f32_16x16x32_bf16(a1u, bfr[t][1],
                                                                 acc[t], 0, 0, 0);
            }
        }
        #pragma unroll
        for (int t = 0; t < 5; ++t)
            #pragma unroll
            for (int reg = 0; reg < 4; ++reg)
                db0[(kg * 4 + reg) * 84 + t * 16 + m] = acc[t][reg];
    }
    // ---- load raw A data for group 1 ----
    if (1 < ngroups) {
        const int tg_a = dir ? (511 - (8 + tl)) : (8 + tl);
        if constexpr (L0) {
            const float* xr = (const float*)in_ +
                              ((size_t)b_a * TT + tg_a) * 32 + kg * 8;
            xraw0 = *(const float4*)xr;
            xraw1 = *(const float4*)(xr + 4);
        } else {
            size_t rowoff = ((size_t)b_a * TT + tg_a) * 24;
            const unsigned short* p0 =
                (kg < 3) ? (r0 + rowoff + 8 * kg) : (r1 + rowoff);
            const unsigned short* p1 =
                (kg == 0) ? (r1 + rowoff + 8) : (r1 + rowoff + 16);
            a0r = *(const bf16x8*)p0;
            a1r = *(const bf16x8*)p1;
        }
    }

    // h pair-words (f16x2), replicated across each 32-lane half; h0 = 0
    unsigned hwd[12];
    #pragma unroll
    for (int k = 0; k < 12; ++k) hwd[k] = 0u;

    int cur = 0;
    for (int g = 0; g < ngroups; ++g) {
        float* Dc = cur ? db1 : db0;
        float* Dn = cur ? db0 : db1;
        wbar();   // D(cur) writes precede in program order (in-order DS)

        // ---- prefetch this group's xg (3 rows x 8 steps) into registers ----
        float xgr[8][3];
        #pragma unroll
        for (int s = 0; s < 8; ++s) {
            const float* xr2 = &Dc[(bl * 8 + s) * 84];
            xgr[s][0] = xr2[u];
            xgr[s][1] = xr2[23 + u];
            xgr[s][2] = xr2[46 + u];
        }

        // ---- MFMA for group g+1 -> Dn (independent work, overlaps scan) ----
        if (g + 1 < ngroups) {
            f32x4 acc[5];
            #pragma unroll
            for (int t = 0; t < 5; ++t)
                acc[t] = (f32x4){bi5[t], bi5[t], bi5[t], bi5[t]};
            if constexpr (L0) {
                float xv[8] = {xraw0.x, xraw0.y, xraw0.z, xraw0.w,
                               xraw1.x, xraw1.y, xraw1.z, xraw1.w};
                bf16x8 afr;
                #pragma unroll
                for (int j = 0; j < 8; ++j)
                    afr[j] = (short)f2bf(xv[j] * an8[j] + cn8[j]);
                #pragma unroll
                for (int t = 0; t < 5; ++t)
                    acc[t] = __builtin_amdgcn_mfma_f32_16x16x32_bf16(
                        afr, bfr[t][0], acc[t], 0, 0, 0);
            } else {
                bf16x8 a0u = a0r;
                bf16x8 a1u = (kg >= 2) ? (bf16x8){0,0,0,0,0,0,0,0} : a1r;
                #pragma unroll
                for (int t = 0; t < 5; ++t) {
                    acc[t] = __builtin_amdgcn_mfma_f32_16x16x32_bf16(
                        a0u, bfr[t][0], acc[t], 0, 0, 0);
                    acc[t] = __builtin_amdgcn_mfma_f32_16x16x32_bf16(
                        a1u, bfr[t][1], acc[t], 0, 0, 0);
                }
            }
            #pragma unroll
            for (int t = 0; t < 5; ++t)
                #pragma unroll
                for (int reg = 0; reg < 4; ++reg)
                    Dn[(kg * 4 + reg) * 84 + t * 16 + m] = acc[t][reg];

            // ---- issue raw A loads for group g+2 ----
            if (g + 2 < ngroups) {
                const int tg_n = dir ? (511 - ((g + 2) * 8 + tl))
                                     : ((g + 2) * 8 + tl);
                if constexpr (L0) {
                    const float* xr = (const float*)in_ +
                                      ((size_t)b_a * TT + tg_n) * 32 + kg * 8;
                    xraw0 = *(const float4*)xr;
                    xraw1 = *(const float4*)(xr + 4);
                } else {
                    size_t rowoff = ((size_t)b_a * TT + tg_n) * 24;
                    const unsigned short* p0 =
                        (kg < 3) ? (r0 + rowoff + 8 * kg) : (r1 + rowoff);
                    const unsigned short* p1 =
                        (kg == 0) ? (r1 + rowoff + 8) : (r1 + rowoff + 16);
                    a0r = *(const bf16x8*)p0;
                    a1r = *(const bf16x8*)p1;
                }
            }
        }

        // ---- 8 scan steps; h broadcast via DPP pack + ds_swizzle (no LDS
        //      round-trip on the critical path) ----
        #pragma unroll
        for (int s8 = 0; s8 < 8; ++s8) {
            // dual accumulators per gate: 6-deep chains
            float a0a = xgr[s8][0], a1a = xgr[s8][1], a2a = bh2;
            float a0b = 0.f, a1b = 0.f, a2b = 0.f;
            #pragma unroll
            for (int k = 0; k < 6; ++k) {
                f16x2 hv = asf16x2(hwd[k]);
                a0a = __builtin_amdgcn_fdot2(asf16x2(wrp[0][k]), hv, a0a, false);
                a1a = __builtin_amdgcn_fdot2(asf16x2(wrp[1][k]), hv, a1a, false);
                a2a = __builtin_amdgcn_fdot2(asf16x2(wrp[2][k]), hv, a2a, false);
            }
            #pragma unroll
            for (int k = 6; k < 12; ++k) {
                f16x2 hv = asf16x2(hwd[k]);
                a0b = __builtin_amdgcn_fdot2(asf16x2(wrp[0][k]), hv, a0b, false);
                a1b = __builtin_amdgcn_fdot2(asf16x2(wrp[1][k]), hv, a1b, false);
                a2b = __builtin_amdgcn_fdot2(asf16x2(wrp[2][k]), hv, a2b, false);
            }
            float r_ = sigm(a0a + a0b);
            float z_ = sigm(a1a + a1b);
            float n_ = tanh_(__builtin_fmaf(r_, a2a + a2b, xgr[s8][2]));
            float hnew = n_ + z_ * (hold - n_);
            hold = hnew;
            if constexpr (LAST) {
                int tg = dir ? (511 - (g * 8 + s8)) : (g * 8 + s8);
                if (u < 23 && tg == TT - 1)
                    lastbuf[bg * 48 + dir * 23 + u] = hnew;
            }
            // pack own pair (h[2p], h[2p+1]) into one f16x2 word:
            // quad_perm(0,0,2,2)=0xA0 (even member), (1,1,3,3)=0xF5 (odd)
            int hb  = __builtin_bit_cast(int, hnew);
            int vlo = __builtin_amdgcn_update_dpp(0, hb, 0xA0, 0xF, 0xF, true);
            int vhi = __builtin_amdgcn_update_dpp(0, hb, 0xF5, 0xF, 0xF, true);
            auto pk = __builtin_amdgcn_cvt_pkrtz(__builtin_bit_cast(float, vlo),
                                                 __builtin_bit_cast(float, vhi));
            unsigned P; __builtin_memcpy(&P, &pk, 4);
            // broadcast pair j from lane 2j of each 32-group:
            // BitMode offset = or_mask<<5 = (2j)<<5 (and=0, xor=0)
            hwd[0]  = (unsigned)__builtin_amdgcn_ds_swizzle((int)P, 0x000);
            hwd[1]  = (unsigned)__builtin_amdgcn_ds_swizzle((int)P, 0x040);
            hwd[2]  = (unsigned)__builtin_amdgcn_ds_swizzle((int)P, 0x080);
            hwd[3]  = (unsigned)__builtin_amdgcn_ds_swizzle((int)P, 0x0C0);
            hwd[4]  = (unsigned)__builtin_amdgcn_ds_swizzle((int)P, 0x100);
            hwd[5]  = (unsigned)__builtin_amdgcn_ds_swizzle((int)P, 0x140);
            hwd[6]  = (unsigned)__builtin_amdgcn_ds_swizzle((int)P, 0x180);
            hwd[7]  = (unsigned)__builtin_amdgcn_ds_swizzle((int)P, 0x1C0);
            hwd[8]  = (unsigned)__builtin_amdgcn_ds_swizzle((int)P, 0x200);
            hwd[9]  = (unsigned)__builtin_amdgcn_ds_swizzle((int)P, 0x240);
            hwd[10] = (unsigned)__builtin_amdgcn_ds_swizzle((int)P, 0x280);
            hwd[11] = (unsigned)__builtin_amdgcn_ds_swizzle((int)P, 0x2C0);
            // store staging (off critical path); lanes 2p,2p+1 dup-write P
            histw[(s8 * 2 + bl) * 16 + (u >> 1)] = P;
        }

        // ---- cooperative coalesced store of the 8-step block ----
        wbar();
        asm volatile("" ::: "memory");
        if constexpr (!LAST) {
            #pragma unroll
            for (int c = 0; c < 3; ++c) {
                f16x2 pf = asf16x2(histw[ldsoff[c]]);
                float lo = (float)pf[0];
                float hi = (cparr[c] == 11) ? 0.f : (float)pf[1];  // col 23 := 0
                unsigned pack = (unsigned)f2bf(lo) | ((unsigned)f2bf(hi) << 16);
                int tg = dir ? (511 - (g * 8 + sarr[c])) : (g * 8 + sarr[c]);
                *(unsigned*)(dstbase + (size_t)tg * 24 + 2 * cparr[c]) = pack;
            }
        }
        wbar();
        cur ^= 1;
    }
}

__global__ __launch_bounds__(256) void fc_kernel(
    const float* __restrict__ last, const float* __restrict__ fcw,
    const float* __restrict__ fcb, const float* __restrict__ ostd,
    const float* __restrict__ omean, float* __restrict__ out)
{
    int idx = blockIdx.x * 256 + threadIdx.x;
    if (idx >= BB * NOUT) return;
    int b = idx >> 3, o = idx & 7;
    float acc = fcb[o];
    const float* lr = last + b * 48;
    const float* wr = fcw + o * 46;
    #pragma unroll
    for (int i = 0; i < 46; i++) acc += lr[i] * wr[i];
    out[idx] = acc * ostd[o] + omean[o];
}

extern "C" void kernel_launch(void* const* d_in, const int* in_sizes, int n_in,
                              void* d_out, int out_size, void* d_ws,
                              size_t ws_size, hipStream_t stream)
{
    const float* x     = (const float*)d_in[0];
    const float* fmean = (const float*)d_in[1];
    const float* fstd  = (const float*)d_in[2];
    const float* omean = (const float*)d_in[3];
    const float* ostd  = (const float*)d_in[4];
    const float* wih0  = (const float*)d_in[5];
    const float* whh0  = (const float*)d_in[6];
    const float* bih0  = (const float*)d_in[7];
    const float* bhh0  = (const float*)d_in[8];
    const float* wihr  = (const float*)d_in[9];
    const float* whhr  = (const float*)d_in[10];
    const float* bihr  = (const float*)d_in[11];
    const float* bhhr  = (const float*)d_in[12];
    const float* fcw   = (const float*)d_in[13];
    const float* fcb   = (const float*)d_in[14];

    char* ws = (char*)d_ws;
    const size_t bufBytes = 2 * DSTRIDE * sizeof(__hip_bfloat16);  // 96 MiB
    __hip_bfloat16* buf0 = (__hip_bfloat16*)ws;
    __hip_bfloat16* buf1 = (__hip_bfloat16*)(ws + bufBytes);
    float* lastb         = (float*)(ws + 2 * bufBytes);

    dim3 grid(BB / 8, 2);

    gru_mfma<true, false><<<grid, 256, 0, stream>>>(
        x, fmean, fstd, wih0, whh0, bih0, bhh0, buf0, nullptr);
    gru_mfma<false, false><<<grid, 256, 0, stream>>>(
        buf0, nullptr, nullptr, wihr + 0 * 2 * 69 * 46, whhr + 0 * 2 * 69 * 23,
        bihr + 0 * 2 * 69, bhhr + 0 * 2 * 69, buf1, nullptr);
    gru_mfma<false, true><<<grid, 256, 0, stream>>>(
        buf1, nullptr, nullptr, wihr + 1 * 2 * 69 * 46, whhr + 1 * 2 * 69 * 23,
        bihr + 1 * 2 * 69, bhhr + 1 * 2 * 69, nullptr, lastb);
    fc_kernel<<<(BB * NOUT + 255) / 256, 256, 0, stream>>>(lastb, fcw, fcb, ostd,
                                                           omean, (float*)d_out);
}

// Round 3
// 625.965 us; speedup vs baseline: 1.0766x; 1.0766x over previous
//
#include <hip/hip_runtime.h>
#include <hip/hip_bf16.h>

constexpr int TT = 512, BB = 2048, NOUT = 8;
constexpr size_t DSTRIDE = (size_t)BB * TT * 24;   // f16 elems per dir region

typedef __attribute__((ext_vector_type(8))) _Float16 f16x8;
typedef __attribute__((ext_vector_type(4))) float f32x4;
typedef __attribute__((ext_vector_type(2))) _Float16 f16x2;

// fast device math: v_exp_f32 / v_rcp_f32 (1-ulp approx, no div sequence)
__device__ __forceinline__ float sigm(float x) {
    float e = __builtin_amdgcn_exp2f(x * -1.4426950408889634f);
    return __builtin_amdgcn_rcpf(1.f + e);
}
__device__ __forceinline__ float tanh_(float x) {
    float e = __builtin_amdgcn_exp2f(x * 2.8853900817779268f);
    return __builtin_fmaf(-2.f, __builtin_amdgcn_rcpf(e + 1.f), 1.f);
}
__device__ __forceinline__ f16x2 asf16x2(unsigned v) {
    f16x2 r; __builtin_memcpy(&r, &v, 4); return r;
}
// v_cvt_pkrtz_f16_f32 with a bit-cast to our f16x2 (builtin returns __fp16x2)
__device__ __forceinline__ f16x2 pkrtz(float a, float b) {
    auto p = __builtin_amdgcn_cvt_pkrtz(a, b);
    f16x2 r; __builtin_memcpy(&r, &p, 4); return r;
}
__device__ __forceinline__ void wbar() { __builtin_amdgcn_wave_barrier(); }

// R12b: R12 with the cvt_pkrtz type fix (memcpy bit-cast helper).
//  - inter-layer data + MFMA in f16 (mfma_f32_16x16x32_f16): store phase is
//    now load-pair/mask/store (no cvt chain), L0 A-prep via v_cvt_pkrtz.
//  - D tile col-major [gate][step], stride 20 f32 (16B-aligned, bank-optimal):
//    5x ds_write_b128 per group (was 20x b32), 6x ds_read_b128 prefetch
//    (was 24x b32).
// Rationale: R11 A/B showed ~6 cy wall per added/removed op (issue-bound,
// VALUBusy 64% at 2 waves/SIMD) -> delete ~12 ops/step.
template <bool L0, bool LAST>
__global__ __launch_bounds__(256) void gru_mfma(
    const void* __restrict__ in_,        // L0: x [B][T][32] f32; else region0 (region1 at +DSTRIDE)
    const float* __restrict__ fmean, const float* __restrict__ fstd,
    const float* __restrict__ wih_g, const float* __restrict__ whh_g,
    const float* __restrict__ bih_g, const float* __restrict__ bhh_g,
    unsigned short* __restrict__ outbuf, float* __restrict__ lastbuf)
{
    constexpr int KIN = L0 ? 32 : 46;
    constexpr int KF  = L0 ? 1 : 2;
    constexpr int DSTR = 20;             // D-tile row stride (f32), 80B

    // [tile t<5][kslot<8][lane m<16][8 halves] staging for B-frags
    __shared__ __align__(16) _Float16  wih_lds[5 * 8 * 16 * 8];
    __shared__ __align__(16) _Float16  whh_h[80 * 24];       // W_hh f16
    __shared__ __align__(16) float     xg_s[4][2][80 * DSTR]; // per-wave D dbuf
    __shared__ __align__(16) _Float16  hist_h[4 * 9 * 2 * 32];  // h history f16
    __shared__ float bih_s[80], bhh_s[80];
    __shared__ __align__(16) float an_s[32], cn_s[32];

    const int tid = threadIdx.x, wv = tid >> 6, lane = tid & 63;
    const int bl = lane >> 5, u = lane & 31;
    const int m  = lane & 15, kg = lane >> 4;             // MFMA lane coords
    const int dir = blockIdx.y;
    const int bg  = blockIdx.x * 8 + wv * 2 + bl;

    const float* wih_d = wih_g + dir * 69 * KIN;
    const float* whh_d = whh_g + dir * 69 * 23;

    // ---- stage W_ih frags [t][kslot][m][8], col-remapped, zero-padded ----
    for (int idx = tid; idx < 5120; idx += 256) {
        int t = idx >> 10, r = idx & 1023;
        int kslot = r >> 7, mm = (r >> 3) & 15, j = r & 7;
        int row = t * 16 + mm, k = kslot * 8 + j;
        float v = 0.f;
        if (row < 69) {
            if constexpr (L0) {
                if (k < 32) v = wih_d[row * 32 + k];
            } else {
                if (k < 23) v = wih_d[row * 46 + k];                      // fwd
                else if (k >= 24 && k < 47) v = wih_d[row * 46 + k - 1];  // bwd
            }
        }
        wih_lds[idx] = (_Float16)v;
    }
    for (int idx = tid; idx < 80 * 24; idx += 256) {
        int j = idx / 24, k = idx - j * 24;
        whh_h[idx] = (j < 69 && k < 23) ? (_Float16)whh_d[j * 23 + k]
                                        : (_Float16)0.f;
    }
    for (int idx = tid; idx < 80; idx += 256) {
        bih_s[idx] = (idx < 69) ? bih_g[dir * 69 + idx] : 0.f;
        bhh_s[idx] = (idx < 69) ? bhh_g[dir * 69 + idx] : 0.f;
    }
    for (int idx = tid; idx < 4 * 9 * 2 * 32; idx += 256)
        hist_h[idx] = (_Float16)0.f;
    if (L0 && tid < 32) {
        float sd = fstd[tid];
        float sa = (sd == 0.f) ? 1.f : sd;        // std==0 -> 1
        float a  = (sa == 1.f) ? 0.f : 1.f / sa;  // adjusted std==1 -> zero
        an_s[tid] = a;
        cn_s[tid] = -fmean[tid] * a;
    }
    __syncthreads();   // only block-wide barrier

    // ---- per-lane W_hh rows (u, 23+u, 46+u) as f16 pairs -> 36 VGPRs ----
    unsigned wrp[3][12];
    float bh2;
    #pragma unroll
    for (int r = 0; r < 3; ++r) {
        int row = r * 23 + u;   // <= 77 < 80
        #pragma unroll
        for (int k = 0; k < 12; ++k)
            wrp[r][k] = *(const unsigned*)&whh_h[row * 24 + 2 * k];
    }
    bh2 = bhh_s[46 + u];   // n-row b_hh stays inside r*(...)
    // D-tile bias: b_ih (+ b_hh for r/z rows, which add outside the r gate)
    float bi5[5];
    #pragma unroll
    for (int t = 0; t < 5; ++t) {
        int n = t * 16 + m;
        bi5[t] = bih_s[n] + (n < 46 ? bhh_s[n] : 0.f);
    }

    // ---- B-fragments register-resident ----
    const f16x8* bfrag = (const f16x8*)wih_lds;   // [t*8+kslot][m]
    f16x8 bfr[5][KF];
    #pragma unroll
    for (int t = 0; t < 5; ++t)
        #pragma unroll
        for (int kf = 0; kf < KF; ++kf)
            bfr[t][kf] = bfrag[(t * 8 + kf * 4 + kg) * 16 + m];

    float an8[L0 ? 8 : 1], cn8[L0 ? 8 : 1];
    if constexpr (L0) {
        #pragma unroll
        for (int j = 0; j < 8; ++j) {
            an8[j] = an_s[kg * 8 + j];
            cn8[j] = cn_s[kg * 8 + j];
        }
    }

    float* db0 = &xg_s[wv][0][0];
    float* db1 = &xg_s[wv][1][0];
    _Float16* hw = &hist_h[wv * 9 * 2 * 32];
    const int ngroups = (LAST && dir == 1) ? 1 : 64;
    float hold = 0.f;

    // ---- store-phase lane constants (hoisted) ----
    int sarr[3], cparr[3], ldsoff[3];
    {
        int idx = lane & 31;
        #pragma unroll
        for (int c = 0; c < 3; ++c) {
            int p = idx + 32 * c;             // 0..95
            sarr[c]  = p / 12;
            cparr[c] = p - 12 * sarr[c];
            ldsoff[c] = ((sarr[c] + 1) * 2 + bl) * 32 + 2 * cparr[c];
        }
    }
    unsigned short* dstbase = nullptr;
    if constexpr (!LAST)
        dstbase = outbuf + dir * DSTRIDE + (size_t)bg * TT * 24;

    // A-row coords: m = bl_a*8 + tl
    const int bl_a = m >> 3, tl = m & 7;
    const int b_a  = blockIdx.x * 8 + wv * 2 + bl_a;

    const unsigned short* r0 = (const unsigned short*)in_;
    const unsigned short* r1 = r0 + DSTRIDE;

    float4 xraw0, xraw1;                 // L0 raw x
    f16x8 a0r, a1r;                      // !L0 f16 frags

    // ---- load raw A data for group 0 ----
    {
        const int tg_a = dir ? (511 - tl) : tl;
        if constexpr (L0) {
            const float* xr = (const float*)in_ +
                              ((size_t)b_a * TT + tg_a) * 32 + kg * 8;
            xraw0 = *(const float4*)xr;
            xraw1 = *(const float4*)(xr + 4);
        } else {
            size_t rowoff = ((size_t)b_a * TT + tg_a) * 24;
            const unsigned short* p0 =
                (kg < 3) ? (r0 + rowoff + 8 * kg) : (r1 + rowoff);
            const unsigned short* p1 =
                (kg == 0) ? (r1 + rowoff + 8) : (r1 + rowoff + 16);
            a0r = *(const f16x8*)p0;
            a1r = *(const f16x8*)p1;
        }
    }

    // ---- prologue: MFMA for group 0 -> db0 ----
    {
        f32x4 acc[5];
        #pragma unroll
        for (int t = 0; t < 5; ++t)
            acc[t] = (f32x4){bi5[t], bi5[t], bi5[t], bi5[t]};
        if constexpr (L0) {
            float xv[8] = {xraw0.x, xraw0.y, xraw0.z, xraw0.w,
                           xraw1.x, xraw1.y, xraw1.z, xraw1.w};
            f16x8 afr;
            #pragma unroll
            for (int j = 0; j < 4; ++j) {
                f16x2 p = pkrtz(xv[2 * j] * an8[2 * j] + cn8[2 * j],
                                xv[2 * j + 1] * an8[2 * j + 1] + cn8[2 * j + 1]);
                afr[2 * j]     = p[0];
                afr[2 * j + 1] = p[1];
            }
            #pragma unroll
            for (int t = 0; t < 5; ++t)
                acc[t] = __builtin_amdgcn_mfma_f32_16x16x32_f16(afr, bfr[t][0],
                                                                acc[t], 0, 0, 0);
        } else {
            f16x8 zz = {};
            f16x8 a0u = a0r;
            f16x8 a1u = (kg >= 2) ? zz : a1r;
            #pragma unroll
            for (int t = 0; t < 5; ++t) {
                acc[t] = __builtin_amdgcn_mfma_f32_16x16x32_f16(a0u, bfr[t][0],
                                                                acc[t], 0, 0, 0);
                acc[t] = __builtin_amdgcn_mfma_f32_16x16x32_f16(a1u, bfr[t][1],
                                                                acc[t], 0, 0, 0);
            }
        }
        #pragma unroll
        for (int t = 0; t < 5; ++t)
            *(f32x4*)&db0[(t * 16 + m) * DSTR + kg * 4] = acc[t];
    }
    // ---- load raw A data for group 1 ----
    if (1 < ngroups) {
        const int tg_a = dir ? (511 - (8 + tl)) : (8 + tl);
        if constexpr (L0) {
            const float* xr = (const float*)in_ +
                              ((size_t)b_a * TT + tg_a) * 32 + kg * 8;
            xraw0 = *(const float4*)xr;
            xraw1 = *(const float4*)(xr + 4);
        } else {
            size_t rowoff = ((size_t)b_a * TT + tg_a) * 24;
            const unsigned short* p0 =
                (kg < 3) ? (r0 + rowoff + 8 * kg) : (r1 + rowoff);
            const unsigned short* p1 =
                (kg == 0) ? (r1 + rowoff + 8) : (r1 + rowoff + 16);
            a0r = *(const f16x8*)p0;
            a1r = *(const f16x8*)p1;
        }
    }

    int cur = 0;
    for (int g = 0; g < ngroups; ++g) {
        float* Dc = cur ? db1 : db0;
        float* Dn = cur ? db0 : db1;
        wbar();   // D(cur) writes precede in program order (in-order DS)

        // ---- prefetch this group's xg: 2x b128 per gate row (col-major D) --
        float xgr[8][3];
        #pragma unroll
        for (int c = 0; c < 3; ++c) {
            const f32x4 lo = *(const f32x4*)&Dc[(c * 23 + u) * DSTR + bl * 8];
            const f32x4 hi = *(const f32x4*)&Dc[(c * 23 + u) * DSTR + bl * 8 + 4];
            #pragma unroll
            for (int s = 0; s < 8; ++s)
                xgr[s][c] = (s < 4) ? lo[s] : hi[s - 4];
        }

        // ---- MFMA for group g+1 -> Dn (independent work, overlaps scan) ----
        if (g + 1 < ngroups) {
            f32x4 acc[5];
            #pragma unroll
            for (int t = 0; t < 5; ++t)
                acc[t] = (f32x4){bi5[t], bi5[t], bi5[t], bi5[t]};
            if constexpr (L0) {
                float xv[8] = {xraw0.x, xraw0.y, xraw0.z, xraw0.w,
                               xraw1.x, xraw1.y, xraw1.z, xraw1.w};
                f16x8 afr;
                #pragma unroll
                for (int j = 0; j < 4; ++j) {
                    f16x2 p = pkrtz(
                        xv[2 * j] * an8[2 * j] + cn8[2 * j],
                        xv[2 * j + 1] * an8[2 * j + 1] + cn8[2 * j + 1]);
                    afr[2 * j]     = p[0];
                    afr[2 * j + 1] = p[1];
                }
                #pragma unroll
                for (int t = 0; t < 5; ++t)
                    acc[t] = __builtin_amdgcn_mfma_f32_16x16x32_f16(
                        afr, bfr[t][0], acc[t], 0, 0, 0);
            } else {
                f16x8 zz = {};
                f16x8 a0u = a0r;
                f16x8 a1u = (kg >= 2) ? zz : a1r;
                #pragma unroll
                for (int t = 0; t < 5; ++t) {
                    acc[t] = __builtin_amdgcn_mfma_f32_16x16x32_f16(
                        a0u, bfr[t][0], acc[t], 0, 0, 0);
                    acc[t] = __builtin_amdgcn_mfma_f32_16x16x32_f16(
                        a1u, bfr[t][1], acc[t], 0, 0, 0);
                }
            }
            #pragma unroll
            for (int t = 0; t < 5; ++t)
                *(f32x4*)&Dn[(t * 16 + m) * DSTR + kg * 4] = acc[t];

            // ---- issue raw A loads for group g+2 ----
            if (g + 2 < ngroups) {
                const int tg_n = dir ? (511 - ((g + 2) * 8 + tl))
                                     : ((g + 2) * 8 + tl);
                if constexpr (L0) {
                    const float* xr = (const float*)in_ +
                                      ((size_t)b_a * TT + tg_n) * 32 + kg * 8;
                    xraw0 = *(const float4*)xr;
                    xraw1 = *(const float4*)(xr + 4);
                } else {
                    size_t rowoff = ((size_t)b_a * TT + tg_n) * 24;
                    const unsigned short* p0 =
                        (kg < 3) ? (r0 + rowoff + 8 * kg) : (r1 + rowoff);
                    const unsigned short* p1 =
                        (kg == 0) ? (r1 + rowoff + 8) : (r1 + rowoff + 16);
                    a0r = *(const f16x8*)p0;
                    a1r = *(const f16x8*)p1;
                }
            }
        }

        // ---- 8 scan steps; h via LDS f16 rows of 32 (unmasked writes) ----
        #pragma unroll
        for (int s8 = 0; s8 < 8; ++s8) {
            const _Float16* hr = &hw[(s8 * 2 + bl) * 32];   // prev h (f16)
            uint4 hq0 = *(const uint4*)hr;          // f16 0..7
            uint4 hq1 = *(const uint4*)(hr + 8);    // f16 8..15
            uint4 hq2 = *(const uint4*)(hr + 16);   // f16 16..23
            unsigned hwd[12] = {hq0.x, hq0.y, hq0.z, hq0.w,
                                hq1.x, hq1.y, hq1.z, hq1.w,
                                hq2.x, hq2.y, hq2.z, hq2.w};
            // dual accumulators per gate: 6-deep chains
            float a0a = xgr[s8][0], a1a = xgr[s8][1], a2a = bh2;
            float a0b = 0.f, a1b = 0.f, a2b = 0.f;
            #pragma unroll
            for (int k = 0; k < 6; ++k) {
                f16x2 hv = asf16x2(hwd[k]);
                a0a = __builtin_amdgcn_fdot2(asf16x2(wrp[0][k]), hv, a0a, false);
                a1a = __builtin_amdgcn_fdot2(asf16x2(wrp[1][k]), hv, a1a, false);
                a2a = __builtin_amdgcn_fdot2(asf16x2(wrp[2][k]), hv, a2a, false);
            }
            #pragma unroll
            for (int k = 6; k < 12; ++k) {
                f16x2 hv = asf16x2(hwd[k]);
                a0b = __builtin_amdgcn_fdot2(asf16x2(wrp[0][k]), hv, a0b, false);
                a1b = __builtin_amdgcn_fdot2(asf16x2(wrp[1][k]), hv, a1b, false);
                a2b = __builtin_amdgcn_fdot2(asf16x2(wrp[2][k]), hv, a2b, false);
            }
            float r_ = sigm(a0a + a0b);
            float z_ = sigm(a1a + a1b);
            float n_ = tanh_(__builtin_fmaf(r_, a2a + a2b, xgr[s8][2]));
            float hnew = n_ + z_ * (hold - n_);
            hold = hnew;
            if constexpr (LAST) {
                int tg = dir ? (511 - (g * 8 + s8)) : (g * 8 + s8);
                if (u < 23 && tg == TT - 1)
                    lastbuf[bg * 48 + dir * 23 + u] = hnew;
            }
            wbar();
            hw[((s8 + 1) * 2 + bl) * 32 + u] = (_Float16)hnew;  // pads land in 24..31
            wbar();   // next step's reads stay after this write (in-order DS)
        }

        // ---- cooperative coalesced store: raw f16 pair words, no cvt ----
        if constexpr (!LAST) {
            #pragma unroll
            for (int c = 0; c < 3; ++c) {
                unsigned w = *(const unsigned*)&hw[ldsoff[c]];
                if (cparr[c] == 11) w &= 0xFFFFu;   // col 23 := 0
                int tg = dir ? (511 - (g * 8 + sarr[c])) : (g * 8 + sarr[c]);
                *(unsigned*)(dstbase + (size_t)tg * 24 + 2 * cparr[c]) = w;
            }
        }
        // carry h into row 0 for next group (disjoint from store-phase rows)
        hw[bl * 32 + u] = (_Float16)hold;
        wbar();
        cur ^= 1;
    }
}

__global__ __launch_bounds__(256) void fc_kernel(
    const float* __restrict__ last, const float* __restrict__ fcw,
    const float* __restrict__ fcb, const float* __restrict__ ostd,
    const float* __restrict__ omean, float* __restrict__ out)
{
    int idx = blockIdx.x * 256 + threadIdx.x;
    if (idx >= BB * NOUT) return;
    int b = idx >> 3, o = idx & 7;
    float acc = fcb[o];
    const float* lr = last + b * 48;
    const float* wr = fcw + o * 46;
    #pragma unroll
    for (int i = 0; i < 46; i++) acc += lr[i] * wr[i];
    out[idx] = acc * ostd[o] + omean[o];
}

extern "C" void kernel_launch(void* const* d_in, const int* in_sizes, int n_in,
                              void* d_out, int out_size, void* d_ws,
                              size_t ws_size, hipStream_t stream)
{
    const float* x     = (const float*)d_in[0];
    const float* fmean = (const float*)d_in[1];
    const float* fstd  = (const float*)d_in[2];
    const float* omean = (const float*)d_in[3];
    const float* ostd  = (const float*)d_in[4];
    const float* wih0  = (const float*)d_in[5];
    const float* whh0  = (const float*)d_in[6];
    const float* bih0  = (const float*)d_in[7];
    const float* bhh0  = (const float*)d_in[8];
    const float* wihr  = (const float*)d_in[9];
    const float* whhr  = (const float*)d_in[10];
    const float* bihr  = (const float*)d_in[11];
    const float* bhhr  = (const float*)d_in[12];
    const float* fcw   = (const float*)d_in[13];
    const float* fcb   = (const float*)d_in[14];

    char* ws = (char*)d_ws;
    const size_t bufBytes = 2 * DSTRIDE * sizeof(unsigned short);  // 96 MiB
    unsigned short* buf0 = (unsigned short*)ws;
    unsigned short* buf1 = (unsigned short*)(ws + bufBytes);
    float* lastb         = (float*)(ws + 2 * bufBytes);

    dim3 grid(BB / 8, 2);

    gru_mfma<true, false><<<grid, 256, 0, stream>>>(
        x, fmean, fstd, wih0, whh0, bih0, bhh0, buf0, nullptr);
    gru_mfma<false, false><<<grid, 256, 0, stream>>>(
        buf0, nullptr, nullptr, wihr + 0 * 2 * 69 * 46, whhr + 0 * 2 * 69 * 23,
        bihr + 0 * 2 * 69, bhhr + 0 * 2 * 69, buf1, nullptr);
    gru_mfma<false, true><<<grid, 256, 0, stream>>>(
        buf1, nullptr, nullptr, wihr + 1 * 2 * 69 * 46, whhr + 1 * 2 * 69 * 23,
        bihr + 1 * 2 * 69, bhhr + 1 * 2 * 69, nullptr, lastb);
    fc_kernel<<<(BB * NOUT + 255) / 256, 256, 0, stream>>>(lastb, fcw, fcb, ostd,
                                                           omean, (float*)d_out);
}

// Round 4
// 616.632 us; speedup vs baseline: 1.0929x; 1.0151x over previous
//
#include <hip/hip_runtime.h>
#include <hip/hip_bf16.h>

constexpr int TT = 512, BB = 2048, NOUT = 8;
constexpr size_t DSTRIDE = (size_t)BB * TT * 24;   // f16 elems per dir region

typedef __attribute__((ext_vector_type(8))) _Float16 f16x8;
typedef __attribute__((ext_vector_type(4))) float f32x4;
typedef __attribute__((ext_vector_type(2))) _Float16 f16x2;

// fast device math: v_exp_f32 / v_rcp_f32 (1-ulp approx, no div sequence)
__device__ __forceinline__ float sigm(float x) {
    float e = __builtin_amdgcn_exp2f(x * -1.4426950408889634f);
    return __builtin_amdgcn_rcpf(1.f + e);
}
__device__ __forceinline__ float tanh_(float x) {
    float e = __builtin_amdgcn_exp2f(x * 2.8853900817779268f);
    return __builtin_fmaf(-2.f, __builtin_amdgcn_rcpf(e + 1.f), 1.f);
}
__device__ __forceinline__ f16x2 asf16x2(unsigned v) {
    f16x2 r; __builtin_memcpy(&r, &v, 4); return r;
}
// v_cvt_pkrtz_f16_f32 with a bit-cast to our f16x2 (builtin returns __fp16x2)
__device__ __forceinline__ f16x2 pkrtz(float a, float b) {
    auto p = __builtin_amdgcn_cvt_pkrtz(a, b);
    f16x2 r; __builtin_memcpy(&r, &p, 4); return r;
}
__device__ __forceinline__ void wbar() { __builtin_amdgcn_wave_barrier(); }

// R13: scheduling unlock. R12b's per-step wave_barrier pair fenced the
// compiler: the group-top MFMA block (~250cy of independent work) could not
// be interleaved into the scan steps' LDS-turnaround/trans stalls. Changes:
//  - per-step wbars removed (hist write row s+1 vs reads row s provably
//    disjoint; next-step read/write overlap keeps the true dep via mayalias)
//  - next-group MFMA/D-write/A-load work manually distributed into the 8
//    step bodies, between hist-read issue and dot consumption:
//      steps 0..4: acc[t] init + MFMA(s) for tile t (+ D-write tile t-1)
//      step 5: D-write tile 4;  step 6: global A-loads for g+2
// Everything else identical to R12b (f16 interlayer, col-major D-tile).
template <bool L0, bool LAST>
__global__ __launch_bounds__(256) void gru_mfma(
    const void* __restrict__ in_,        // L0: x [B][T][32] f32; else region0 (region1 at +DSTRIDE)
    const float* __restrict__ fmean, const float* __restrict__ fstd,
    const float* __restrict__ wih_g, const float* __restrict__ whh_g,
    const float* __restrict__ bih_g, const float* __restrict__ bhh_g,
    unsigned short* __restrict__ outbuf, float* __restrict__ lastbuf)
{
    constexpr int KIN = L0 ? 32 : 46;
    constexpr int KF  = L0 ? 1 : 2;
    constexpr int DSTR = 20;             // D-tile row stride (f32), 80B

    // [tile t<5][kslot<8][lane m<16][8 halves] staging for B-frags
    __shared__ __align__(16) _Float16  wih_lds[5 * 8 * 16 * 8];
    __shared__ __align__(16) _Float16  whh_h[80 * 24];       // W_hh f16
    __shared__ __align__(16) float     xg_s[4][2][80 * DSTR]; // per-wave D dbuf
    __shared__ __align__(16) _Float16  hist_h[4 * 9 * 2 * 32];  // h history f16
    __shared__ float bih_s[80], bhh_s[80];
    __shared__ __align__(16) float an_s[32], cn_s[32];

    const int tid = threadIdx.x, wv = tid >> 6, lane = tid & 63;
    const int bl = lane >> 5, u = lane & 31;
    const int m  = lane & 15, kg = lane >> 4;             // MFMA lane coords
    const int dir = blockIdx.y;
    const int bg  = blockIdx.x * 8 + wv * 2 + bl;

    const float* wih_d = wih_g + dir * 69 * KIN;
    const float* whh_d = whh_g + dir * 69 * 23;

    // ---- stage W_ih frags [t][kslot][m][8], col-remapped, zero-padded ----
    for (int idx = tid; idx < 5120; idx += 256) {
        int t = idx >> 10, r = idx & 1023;
        int kslot = r >> 7, mm = (r >> 3) & 15, j = r & 7;
        int row = t * 16 + mm, k = kslot * 8 + j;
        float v = 0.f;
        if (row < 69) {
            if constexpr (L0) {
                if (k < 32) v = wih_d[row * 32 + k];
            } else {
                if (k < 23) v = wih_d[row * 46 + k];                      // fwd
                else if (k >= 24 && k < 47) v = wih_d[row * 46 + k - 1];  // bwd
            }
        }
        wih_lds[idx] = (_Float16)v;
    }
    for (int idx = tid; idx < 80 * 24; idx += 256) {
        int j = idx / 24, k = idx - j * 24;
        whh_h[idx] = (j < 69 && k < 23) ? (_Float16)whh_d[j * 23 + k]
                                        : (_Float16)0.f;
    }
    for (int idx = tid; idx < 80; idx += 256) {
        bih_s[idx] = (idx < 69) ? bih_g[dir * 69 + idx] : 0.f;
        bhh_s[idx] = (idx < 69) ? bhh_g[dir * 69 + idx] : 0.f;
    }
    for (int idx = tid; idx < 4 * 9 * 2 * 32; idx += 256)
        hist_h[idx] = (_Float16)0.f;
    if (L0 && tid < 32) {
        float sd = fstd[tid];
        float sa = (sd == 0.f) ? 1.f : sd;        // std==0 -> 1
        float a  = (sa == 1.f) ? 0.f : 1.f / sa;  // adjusted std==1 -> zero
        an_s[tid] = a;
        cn_s[tid] = -fmean[tid] * a;
    }
    __syncthreads();   // only block-wide barrier

    // ---- per-lane W_hh rows (u, 23+u, 46+u) as f16 pairs -> 36 VGPRs ----
    unsigned wrp[3][12];
    float bh2;
    #pragma unroll
    for (int r = 0; r < 3; ++r) {
        int row = r * 23 + u;   // <= 77 < 80
        #pragma unroll
        for (int k = 0; k < 12; ++k)
            wrp[r][k] = *(const unsigned*)&whh_h[row * 24 + 2 * k];
    }
    bh2 = bhh_s[46 + u];   // n-row b_hh stays inside r*(...)
    // D-tile bias: b_ih (+ b_hh for r/z rows, which add outside the r gate)
    float bi5[5];
    #pragma unroll
    for (int t = 0; t < 5; ++t) {
        int n = t * 16 + m;
        bi5[t] = bih_s[n] + (n < 46 ? bhh_s[n] : 0.f);
    }

    // ---- B-fragments register-resident ----
    const f16x8* bfrag = (const f16x8*)wih_lds;   // [t*8+kslot][m]
    f16x8 bfr[5][KF];
    #pragma unroll
    for (int t = 0; t < 5; ++t)
        #pragma unroll
        for (int kf = 0; kf < KF; ++kf)
            bfr[t][kf] = bfrag[(t * 8 + kf * 4 + kg) * 16 + m];

    float an8[L0 ? 8 : 1], cn8[L0 ? 8 : 1];
    if constexpr (L0) {
        #pragma unroll
        for (int j = 0; j < 8; ++j) {
            an8[j] = an_s[kg * 8 + j];
            cn8[j] = cn_s[kg * 8 + j];
        }
    }

    float* db0 = &xg_s[wv][0][0];
    float* db1 = &xg_s[wv][1][0];
    _Float16* hw = &hist_h[wv * 9 * 2 * 32];
    const int ngroups = (LAST && dir == 1) ? 1 : 64;
    float hold = 0.f;

    // ---- store-phase lane constants (hoisted) ----
    int sarr[3], cparr[3], ldsoff[3];
    {
        int idx = lane & 31;
        #pragma unroll
        for (int c = 0; c < 3; ++c) {
            int p = idx + 32 * c;             // 0..95
            sarr[c]  = p / 12;
            cparr[c] = p - 12 * sarr[c];
            ldsoff[c] = ((sarr[c] + 1) * 2 + bl) * 32 + 2 * cparr[c];
        }
    }
    unsigned short* dstbase = nullptr;
    if constexpr (!LAST)
        dstbase = outbuf + dir * DSTRIDE + (size_t)bg * TT * 24;

    // A-row coords: m = bl_a*8 + tl
    const int bl_a = m >> 3, tl = m & 7;
    const int b_a  = blockIdx.x * 8 + wv * 2 + bl_a;

    const unsigned short* r0 = (const unsigned short*)in_;
    const unsigned short* r1 = r0 + DSTRIDE;

    float4 xraw0, xraw1;                 // L0 raw x
    f16x8 a0r, a1r;                      // !L0 f16 frags

    // ---- load raw A data for group 0 ----
    {
        const int tg_a = dir ? (511 - tl) : tl;
        if constexpr (L0) {
            const float* xr = (const float*)in_ +
                              ((size_t)b_a * TT + tg_a) * 32 + kg * 8;
            xraw0 = *(const float4*)xr;
            xraw1 = *(const float4*)(xr + 4);
        } else {
            size_t rowoff = ((size_t)b_a * TT + tg_a) * 24;
            const unsigned short* p0 =
                (kg < 3) ? (r0 + rowoff + 8 * kg) : (r1 + rowoff);
            const unsigned short* p1 =
                (kg == 0) ? (r1 + rowoff + 8) : (r1 + rowoff + 16);
            a0r = *(const f16x8*)p0;
            a1r = *(const f16x8*)p1;
        }
    }

    // ---- prologue: MFMA for group 0 -> db0 (monolithic, once) ----
    {
        f32x4 acc[5];
        #pragma unroll
        for (int t = 0; t < 5; ++t)
            acc[t] = (f32x4){bi5[t], bi5[t], bi5[t], bi5[t]};
        if constexpr (L0) {
            float xv[8] = {xraw0.x, xraw0.y, xraw0.z, xraw0.w,
                           xraw1.x, xraw1.y, xraw1.z, xraw1.w};
            f16x8 afr;
            #pragma unroll
            for (int j = 0; j < 4; ++j) {
                f16x2 p = pkrtz(xv[2 * j] * an8[2 * j] + cn8[2 * j],
                                xv[2 * j + 1] * an8[2 * j + 1] + cn8[2 * j + 1]);
                afr[2 * j]     = p[0];
                afr[2 * j + 1] = p[1];
            }
            #pragma unroll
            for (int t = 0; t < 5; ++t)
                acc[t] = __builtin_amdgcn_mfma_f32_16x16x32_f16(afr, bfr[t][0],
                                                                acc[t], 0, 0, 0);
        } else {
            f16x8 zz = {};
            f16x8 a0u = a0r;
            f16x8 a1u = (kg >= 2) ? zz : a1r;
            #pragma unroll
            for (int t = 0; t < 5; ++t) {
                acc[t] = __builtin_amdgcn_mfma_f32_16x16x32_f16(a0u, bfr[t][0],
                                                                acc[t], 0, 0, 0);
                acc[t] = __builtin_amdgcn_mfma_f32_16x16x32_f16(a1u, bfr[t][1],
                                                                acc[t], 0, 0, 0);
            }
        }
        #pragma unroll
        for (int t = 0; t < 5; ++t)
            *(f32x4*)&db0[(t * 16 + m) * DSTR + kg * 4] = acc[t];
    }
    // ---- load raw A data for group 1 ----
    if (1 < ngroups) {
        const int tg_a = dir ? (511 - (8 + tl)) : (8 + tl);
        if constexpr (L0) {
            const float* xr = (const float*)in_ +
                              ((size_t)b_a * TT + tg_a) * 32 + kg * 8;
            xraw0 = *(const float4*)xr;
            xraw1 = *(const float4*)(xr + 4);
        } else {
            size_t rowoff = ((size_t)b_a * TT + tg_a) * 24;
            const unsigned short* p0 =
                (kg < 3) ? (r0 + rowoff + 8 * kg) : (r1 + rowoff);
            const unsigned short* p1 =
                (kg == 0) ? (r1 + rowoff + 8) : (r1 + rowoff + 16);
            a0r = *(const f16x8*)p0;
            a1r = *(const f16x8*)p1;
        }
    }

    int cur = 0;
    for (int g = 0; g < ngroups; ++g) {
        float* Dc = cur ? db1 : db0;
        float* Dn = cur ? db0 : db1;
        wbar();   // D(cur) writes precede in program order (in-order DS)

        // ---- prefetch this group's xg: 2x b128 per gate row (col-major D) --
        float xgr[8][3];
        #pragma unroll
        for (int c = 0; c < 3; ++c) {
            const f32x4 lo = *(const f32x4*)&Dc[(c * 23 + u) * DSTR + bl * 8];
            const f32x4 hi = *(const f32x4*)&Dc[(c * 23 + u) * DSTR + bl * 8 + 4];
            #pragma unroll
            for (int s = 0; s < 8; ++s)
                xgr[s][c] = (s < 4) ? lo[s] : hi[s - 4];
        }

        const bool domfma = (g + 1 < ngroups);
        const bool doload = (g + 2 < ngroups);
        f32x4 acc[5];
        f16x8 a0u, a1u, afr;

        // ---- 8 scan steps with next-group work interleaved ----
        #pragma unroll
        for (int s8 = 0; s8 < 8; ++s8) {
            const _Float16* hr = &hw[(s8 * 2 + bl) * 32];   // prev h (f16)
            uint4 hq0 = *(const uint4*)hr;          // f16 0..7
            uint4 hq1 = *(const uint4*)(hr + 8);    // f16 8..15
            uint4 hq2 = *(const uint4*)(hr + 16);   // f16 16..23

            // ---- interleave chunk: fills hist-read latency ----
            if (s8 <= 4) {
                if (domfma) {
                    if constexpr (L0) {
                        if (s8 == 0) {
                            float xv[8] = {xraw0.x, xraw0.y, xraw0.z, xraw0.w,
                                           xraw1.x, xraw1.y, xraw1.z, xraw1.w};
                            #pragma unroll
                            for (int j = 0; j < 4; ++j) {
                                f16x2 p = pkrtz(
                                    xv[2 * j] * an8[2 * j] + cn8[2 * j],
                                    xv[2 * j + 1] * an8[2 * j + 1] + cn8[2 * j + 1]);
                                afr[2 * j]     = p[0];
                                afr[2 * j + 1] = p[1];
                            }
                        }
                        acc[s8] = (f32x4){bi5[s8], bi5[s8], bi5[s8], bi5[s8]};
                        acc[s8] = __builtin_amdgcn_mfma_f32_16x16x32_f16(
                            afr, bfr[s8][0], acc[s8], 0, 0, 0);
                    } else {
                        if (s8 == 0) {
                            f16x8 zz = {};
                            a0u = a0r;
                            a1u = (kg >= 2) ? zz : a1r;
                        }
                        acc[s8] = (f32x4){bi5[s8], bi5[s8], bi5[s8], bi5[s8]};
                        acc[s8] = __builtin_amdgcn_mfma_f32_16x16x32_f16(
                            a0u, bfr[s8][0], acc[s8], 0, 0, 0);
                        acc[s8] = __builtin_amdgcn_mfma_f32_16x16x32_f16(
                            a1u, bfr[s8][1], acc[s8], 0, 0, 0);
                    }
                    if (s8 >= 1)
                        *(f32x4*)&Dn[((s8 - 1) * 16 + m) * DSTR + kg * 4] =
                            acc[s8 - 1];
                }
            } else if (s8 == 5) {
                if (domfma)
                    *(f32x4*)&Dn[(4 * 16 + m) * DSTR + kg * 4] = acc[4];
            } else if (s8 == 6) {
                if (doload) {
                    const int tg_n = dir ? (511 - ((g + 2) * 8 + tl))
                                         : ((g + 2) * 8 + tl);
                    if constexpr (L0) {
                        const float* xr = (const float*)in_ +
                                          ((size_t)b_a * TT + tg_n) * 32 + kg * 8;
                        xraw0 = *(const float4*)xr;
                        xraw1 = *(const float4*)(xr + 4);
                    } else {
                        size_t rowoff = ((size_t)b_a * TT + tg_n) * 24;
                        const unsigned short* p0 =
                            (kg < 3) ? (r0 + rowoff + 8 * kg) : (r1 + rowoff);
                        const unsigned short* p1 =
                            (kg == 0) ? (r1 + rowoff + 8) : (r1 + rowoff + 16);
                        a0r = *(const f16x8*)p0;
                        a1r = *(const f16x8*)p1;
                    }
                }
            }

            // ---- dots + gates ----
            unsigned hwd[12] = {hq0.x, hq0.y, hq0.z, hq0.w,
                                hq1.x, hq1.y, hq1.z, hq1.w,
                                hq2.x, hq2.y, hq2.z, hq2.w};
            // dual accumulators per gate: 6-deep chains
            float a0a = xgr[s8][0], a1a = xgr[s8][1], a2a = bh2;
            float a0b = 0.f, a1b = 0.f, a2b = 0.f;
            #pragma unroll
            for (int k = 0; k < 6; ++k) {
                f16x2 hv = asf16x2(hwd[k]);
                a0a = __builtin_amdgcn_fdot2(asf16x2(wrp[0][k]), hv, a0a, false);
                a1a = __builtin_amdgcn_fdot2(asf16x2(wrp[1][k]), hv, a1a, false);
                a2a = __builtin_amdgcn_fdot2(asf16x2(wrp[2][k]), hv, a2a, false);
            }
            #pragma unroll
            for (int k = 6; k < 12; ++k) {
                f16x2 hv = asf16x2(hwd[k]);
                a0b = __builtin_amdgcn_fdot2(asf16x2(wrp[0][k]), hv, a0b, false);
                a1b = __builtin_amdgcn_fdot2(asf16x2(wrp[1][k]), hv, a1b, false);
                a2b = __builtin_amdgcn_fdot2(asf16x2(wrp[2][k]), hv, a2b, false);
            }
            float r_ = sigm(a0a + a0b);
            float z_ = sigm(a1a + a1b);
            float n_ = tanh_(__builtin_fmaf(r_, a2a + a2b, xgr[s8][2]));
            float hnew = n_ + z_ * (hold - n_);
            hold = hnew;
            if constexpr (LAST) {
                int tg = dir ? (511 - (g * 8 + s8)) : (g * 8 + s8);
                if (u < 23 && tg == TT - 1)
                    lastbuf[bg * 48 + dir * 23 + u] = hnew;
            }
            hw[((s8 + 1) * 2 + bl) * 32 + u] = (_Float16)hnew;  // pads in 24..31
        }

        wbar();   // steps' hist writes precede store-phase reads

        // ---- cooperative coalesced store: raw f16 pair words, no cvt ----
        if constexpr (!LAST) {
            #pragma unroll
            for (int c = 0; c < 3; ++c) {
                unsigned w = *(const unsigned*)&hw[ldsoff[c]];
                if (cparr[c] == 11) w &= 0xFFFFu;   // col 23 := 0
                int tg = dir ? (511 - (g * 8 + sarr[c])) : (g * 8 + sarr[c]);
                *(unsigned*)(dstbase + (size_t)tg * 24 + 2 * cparr[c]) = w;
            }
        }
        // carry h into row 0 for next group (disjoint from store-phase rows)
        hw[bl * 32 + u] = (_Float16)hold;
        wbar();
        cur ^= 1;
    }
}

__global__ __launch_bounds__(256) void fc_kernel(
    const float* __restrict__ last, const float* __restrict__ fcw,
    const float* __restrict__ fcb, const float* __restrict__ ostd,
    const float* __restrict__ omean, float* __restrict__ out)
{
    int idx = blockIdx.x * 256 + threadIdx.x;
    if (idx >= BB * NOUT) return;
    int b = idx >> 3, o = idx & 7;
    float acc = fcb[o];
    const float* lr = last + b * 48;
    const float* wr = fcw + o * 46;
    #pragma unroll
    for (int i = 0; i < 46; i++) acc += lr[i] * wr[i];
    out[idx] = acc * ostd[o] + omean[o];
}

extern "C" void kernel_launch(void* const* d_in, const int* in_sizes, int n_in,
                              void* d_out, int out_size, void* d_ws,
                              size_t ws_size, hipStream_t stream)
{
    const float* x     = (const float*)d_in[0];
    const float* fmean = (const float*)d_in[1];
    const float* fstd  = (const float*)d_in[2];
    const float* omean = (const float*)d_in[3];
    const float* ostd  = (const float*)d_in[4];
    const float* wih0  = (const float*)d_in[5];
    const float* whh0  = (const float*)d_in[6];
    const float* bih0  = (const float*)d_in[7];
    const float* bhh0  = (const float*)d_in[8];
    const float* wihr  = (const float*)d_in[9];
    const float* whhr  = (const float*)d_in[10];
    const float* bihr  = (const float*)d_in[11];
    const float* bhhr  = (const float*)d_in[12];
    const float* fcw   = (const float*)d_in[13];
    const float* fcb   = (const float*)d_in[14];

    char* ws = (char*)d_ws;
    const size_t bufBytes = 2 * DSTRIDE * sizeof(unsigned short);  // 96 MiB
    unsigned short* buf0 = (unsigned short*)ws;
    unsigned short* buf1 = (unsigned short*)(ws + bufBytes);
    float* lastb         = (float*)(ws + 2 * bufBytes);

    dim3 grid(BB / 8, 2);

    gru_mfma<true, false><<<grid, 256, 0, stream>>>(
        x, fmean, fstd, wih0, whh0, bih0, bhh0, buf0, nullptr);
    gru_mfma<false, false><<<grid, 256, 0, stream>>>(
        buf0, nullptr, nullptr, wihr + 0 * 2 * 69 * 46, whhr + 0 * 2 * 69 * 23,
        bihr + 0 * 2 * 69, bhhr + 0 * 2 * 69, buf1, nullptr);
    gru_mfma<false, true><<<grid, 256, 0, stream>>>(
        buf1, nullptr, nullptr, wihr + 1 * 2 * 69 * 46, whhr + 1 * 2 * 69 * 23,
        bihr + 1 * 2 * 69, bhhr + 1 * 2 * 69, nullptr, lastb);
    fc_kernel<<<(BB * NOUT + 255) / 256, 256, 0, stream>>>(lastb, fcw, fcb, ostd,
                                                           omean, (float*)d_out);
}